// Round 1
// baseline (102.643 us; speedup 1.0000x reference)
//
#include <hip/hip_runtime.h>
#include <math.h>

#define N 512

struct F3 { float x, y, z; };

__device__ __forceinline__ F3 f3sub(F3 a, F3 b) { return {a.x - b.x, a.y - b.y, a.z - b.z}; }
__device__ __forceinline__ F3 f3cross(F3 a, F3 b) {
    return {a.y * b.z - a.z * b.y, a.z * b.x - a.x * b.z, a.x * b.y - a.y * b.x};
}
__device__ __forceinline__ float f3dot(F3 a, F3 b) { return a.x * b.x + a.y * b.y + a.z * b.z; }

__global__ __launch_bounds__(256) void writhe_kernel(const float* __restrict__ x,
                                                     const int* __restrict__ seg,
                                                     int S,
                                                     float* __restrict__ out) {
    __shared__ float xs[N * 3];
    const int batch = blockIdx.y;
    const float* xb = x + (size_t)batch * (N * 3);
    for (int i = threadIdx.x; i < N * 3; i += blockDim.x) xs[i] = xb[i];
    __syncthreads();

    const int s = blockIdx.x * blockDim.x + threadIdx.x;
    if (s >= S) return;

    const int4 sg = ((const int4*)seg)[s];  // (a, a+1, b, b+1)
    const int a = sg.x, a1 = sg.y, b = sg.z, b1 = sg.w;

    F3 p0 = {xs[3 * a], xs[3 * a + 1], xs[3 * a + 2]};
    F3 p1 = {xs[3 * a1], xs[3 * a1 + 1], xs[3 * a1 + 2]};
    F3 p2 = {xs[3 * b], xs[3 * b + 1], xs[3 * b + 2]};
    F3 p3 = {xs[3 * b1], xs[3 * b1 + 1], xs[3 * b1 + 2]};

    // Normalization of d* cancels in normalized crosses and doesn't change the sign term.
    F3 d0 = f3sub(p2, p0), d1 = f3sub(p3, p0), d2 = f3sub(p2, p1), d3 = f3sub(p3, p1);

    F3 c0 = f3cross(d0, d1);
    F3 c1 = f3cross(d1, d3);
    F3 c2 = f3cross(d3, d2);
    F3 c3 = f3cross(d2, d0);

    float r0 = rsqrtf(f3dot(c0, c0));
    float r1 = rsqrtf(f3dot(c1, c1));
    float r2 = rsqrtf(f3dot(c2, c2));
    float r3 = rsqrtf(f3dot(c3, c3));

    float t01 = fminf(1.f, fmaxf(-1.f, f3dot(c0, c1) * (r0 * r1)));
    float t12 = fminf(1.f, fmaxf(-1.f, f3dot(c1, c2) * (r1 * r2)));
    float t23 = fminf(1.f, fmaxf(-1.f, f3dot(c2, c3) * (r2 * r3)));
    float t30 = fminf(1.f, fmaxf(-1.f, f3dot(c3, c0) * (r3 * r0)));

    float omega = asinf(t01) + asinf(t12) + asinf(t23) + asinf(t30);

    F3 e = f3cross(f3sub(p3, p2), f3sub(p1, p0));
    float sv = f3dot(e, d0);
    float sgn = (sv > 0.f) ? 1.f : ((sv < 0.f) ? -1.f : 0.f);

    float wr = omega * sgn * 0.15915494309189535f;  // 1/(2*pi)

    float* ob = out + (size_t)batch * (N * N);
    // Final scatter after resolving the reference's sequential .set overwrite semantics:
    // set2 target (a+1,b+1) always survives; set1 target (a,b) survives only for a==0.
    ob[(size_t)a1 * N + b1] = wr;
    ob[(size_t)b1 * N + a1] = wr;
    if (a == 0) {
        ob[b] = wr;
        ob[(size_t)b * N] = wr;
    }
}

extern "C" void kernel_launch(void* const* d_in, const int* in_sizes, int n_in,
                              void* d_out, int out_size, void* d_ws, size_t ws_size,
                              hipStream_t stream) {
    const float* x = (const float*)d_in[0];
    const int* seg = (const int*)d_in[1];
    float* out = (float*)d_out;

    const int S = in_sizes[1] / 4;       // number of segments (129795)
    const int B = in_sizes[0] / (N * 3); // batch (32)

    hipMemsetAsync(d_out, 0, (size_t)out_size * sizeof(float), stream);

    dim3 block(256);
    dim3 grid((S + 255) / 256, B);
    writhe_kernel<<<grid, block, 0, stream>>>(x, seg, S, out);
}

// Round 2
// 92.420 us; speedup vs baseline: 1.1106x; 1.1106x over previous
//
#include <hip/hip_runtime.h>
#include <math.h>

#define N 512
#define TILE 32

struct F3 { float x, y, z; };

__device__ __forceinline__ F3 f3sub(F3 a, F3 b) { return {a.x - b.x, a.y - b.y, a.z - b.z}; }
__device__ __forceinline__ F3 f3cross(F3 a, F3 b) {
    return {a.y * b.z - a.z * b.y, a.z * b.x - a.x * b.z, a.x * b.y - a.y * b.x};
}
__device__ __forceinline__ float f3dot(F3 a, F3 b) { return a.x * b.x + a.y * b.y + a.z * b.z; }

// Writhe contribution for segment pair using atoms (a, a+1, b, b+1) from LDS coords.
__device__ __forceinline__ float wr_val(const float* xs, int a, int b) {
    const float* pa = xs + 3 * a;
    const float* pb = xs + 3 * b;
    F3 p0 = {pa[0], pa[1], pa[2]};
    F3 p1 = {pa[3], pa[4], pa[5]};
    F3 p2 = {pb[0], pb[1], pb[2]};
    F3 p3 = {pb[3], pb[4], pb[5]};

    // Normalization of displacements cancels in normalized crosses and in the sign term.
    F3 d0 = f3sub(p2, p0), d1 = f3sub(p3, p0), d2 = f3sub(p2, p1), d3 = f3sub(p3, p1);

    F3 c0 = f3cross(d0, d1);
    F3 c1 = f3cross(d1, d3);
    F3 c2 = f3cross(d3, d2);
    F3 c3 = f3cross(d2, d0);

    float r0 = rsqrtf(f3dot(c0, c0));
    float r1 = rsqrtf(f3dot(c1, c1));
    float r2 = rsqrtf(f3dot(c2, c2));
    float r3 = rsqrtf(f3dot(c3, c3));

    float t01 = fminf(1.f, fmaxf(-1.f, f3dot(c0, c1) * (r0 * r1)));
    float t12 = fminf(1.f, fmaxf(-1.f, f3dot(c1, c2) * (r1 * r2)));
    float t23 = fminf(1.f, fmaxf(-1.f, f3dot(c2, c3) * (r2 * r3)));
    float t30 = fminf(1.f, fmaxf(-1.f, f3dot(c3, c0) * (r3 * r0)));

    float omega = asinf(t01) + asinf(t12) + asinf(t23) + asinf(t30);

    F3 e = f3cross(f3sub(p3, p2), f3sub(p1, p0));
    float sv = f3dot(e, d0);
    float sgn = (sv > 0.f) ? 1.f : ((sv < 0.f) ? -1.f : 0.f);

    return omega * sgn * 0.15915494309189535f;  // 1/(2*pi)
}

// One block per (upper-triangle tile pair, batch). Computes a 32x32 output tile,
// writes it and its transpose fully coalesced (zeros included -> no memset pass).
__global__ __launch_bounds__(256) void writhe_tile(const float* __restrict__ x,
                                                   float* __restrict__ out) {
    __shared__ float xs[N * 3];
    __shared__ float ts[TILE][TILE + 1];

    const int batch = blockIdx.y;
    const float* xb = x + (size_t)batch * (N * 3);
    {
        const float4* src = (const float4*)xb;
        float4* dst = (float4*)xs;
        for (int i = threadIdx.x; i < (N * 3) / 4; i += blockDim.x) dst[i] = src[i];
    }

    // Map blockIdx.x -> (ti, tj), ti <= tj, among 16x16 tiles (136 pairs).
    int p = blockIdx.x;
    int ti = 0;
    while (p >= (N / TILE) - ti) { p -= (N / TILE) - ti; ++ti; }
    const int tj = ti + p;

    __syncthreads();

    const int c = threadIdx.x & 31;
    const int r0 = threadIdx.x >> 5;
    const bool diag = (ti == tj);

    float* ob = out + (size_t)batch * (N * N);

#pragma unroll
    for (int k = 0; k < 4; ++k) {
        const int r = r0 + 8 * k;
        const int gi = ti * TILE + r;
        const int gj = tj * TILE + c;
        const int lo = min(gi, gj), hi = max(gi, gj);
        bool valid;
        int a, b;
        if (lo == 0) { valid = (hi >= 2) && (hi <= 510); a = 0; b = hi; }
        else         { valid = (hi >= lo + 2);           a = lo - 1; b = hi - 1; }
        float v = 0.f;
        if (valid) v = wr_val(xs, a, b);
        ob[(size_t)gi * N + gj] = v;
        if (!diag) ts[r][c] = v;
    }

    if (!diag) {
        __syncthreads();
#pragma unroll
        for (int k = 0; k < 4; ++k) {
            const int r = r0 + 8 * k;
            ob[(size_t)(tj * TILE + r) * N + (ti * TILE + c)] = ts[c][r];
        }
    }
}

extern "C" void kernel_launch(void* const* d_in, const int* in_sizes, int n_in,
                              void* d_out, int out_size, void* d_ws, size_t ws_size,
                              hipStream_t stream) {
    const float* x = (const float*)d_in[0];
    float* out = (float*)d_out;
    const int B = in_sizes[0] / (N * 3);

    const int ntiles = N / TILE;                 // 16
    const int npairs = ntiles * (ntiles + 1) / 2;  // 136

    dim3 block(256);
    dim3 grid(npairs, B);
    writhe_tile<<<grid, block, 0, stream>>>(x, out);
}